// Round 1
// baseline (87621.692 us; speedup 1.0000x reference)
//
#include <hip/hip_runtime.h>
#include <cstdint>

#define TSTEPS 8192
#define FIN 256
#define HD 1024
#define ED 512

#define AG __HIP_MEMORY_SCOPE_AGENT

// ---------------- ws layout (uint32 units) ----------------
// c1prod[i]  @ i*64        (i = 0..7, 256B apart)  L1 production counter banks
// c1cons[i]  @ 512 + i*64                          L2 "staged h1" counter banks
// c2prod[i]  @ 1024 + i*64                         L2 production counter banks
// h1buf      @ 2048: float[2][1024]   (2-slot ring)
// h2buf      @ 2048 + 2048: float[2][512]

__device__ __forceinline__ float sigf(float z) { return 1.0f / (1.0f + expf(-z)); }

__global__ void zero_ctrs(uint32_t* ws) {
  int i = threadIdx.x;
  if (i < 24) ws[i * 64] = 0u;   // zero all 24 counter banks (d_ws is poisoned 0xAA)
}

// wave 0 spins on up to 2 counter groups (8 banks each); other waves park at barrier.
__device__ __forceinline__ void wg_wait(uint32_t* ws, int wave, int lane,
                                        uint32_t prodBase, uint32_t prodTgt,
                                        uint32_t consBase, uint32_t consTgt) {
  if (wave == 0) {
    uint32_t ofs = (lane < 8) ? (prodBase + (uint32_t)lane * 64u)
                 : ((lane < 16) ? (consBase + (uint32_t)(lane - 8) * 64u) : prodBase);
    uint32_t tgt = (lane < 8) ? prodTgt : ((lane < 16) ? consTgt : 0u);
    for (;;) {
      uint32_t v = __hip_atomic_load(&ws[ofs], __ATOMIC_RELAXED, AG);
      if (__all(v >= tgt)) break;
    }
  }
  __syncthreads();
}

// Persistent fused 2-layer LSTM. 384 wgs x 256 thr:
//   wgs 0..255  : layer 1, wave w owns h1-index hb = bid*4+w (4 gate rows in regs)
//   wgs 256..383: layer 2 (lags L1 by 1..2 steps), wave w owns h2-index e = (bid-256)*4+w
// All weights live in VGPRs for the whole kernel. Cross-wg h exchange via
// agent-scope atomics (coherence-point reads/writes; per-XCD L2 staleness impossible).
__global__ void __launch_bounds__(256, 2) lstm2_fused(
    const float* __restrict__ x,
    const float* __restrict__ w_ih1, const float* __restrict__ w_hh1,
    const float* __restrict__ b_ih1, const float* __restrict__ b_hh1,
    const float* __restrict__ w_ih2, const float* __restrict__ w_hh2,
    const float* __restrict__ b_ih2, const float* __restrict__ b_hh2,
    float* __restrict__ out, uint32_t* __restrict__ ws)
{
  float* h1buf = (float*)(ws + 2048);   // [2][HD]
  float* h2buf = h1buf + 2 * HD;        // [2][ED]

  const int bid  = blockIdx.x;
  const int tid  = threadIdx.x;
  const int wave = tid >> 6;
  const int lane = tid & 63;

  __shared__ float4 hsl[256];   // h1 staging, XOR-swizzled float4 slots
  __shared__ float4 h2l[128];   // h2 staging (L2 only)

  if (bid < 256) {
    // ------------------------- layer 1 -------------------------
    const int hb = bid * 4 + wave;                     // h1 index 0..1023
    float whh[4][16], wih[4][4], bz[4];
#pragma unroll
    for (int g = 0; g < 4; ++g) {
      const size_t row = (size_t)g * HD + hb;          // PyTorch gate order i,f,g,o
      const float* wr = w_hh1 + row * HD + lane * 16;  // lane k-chunk [16l,16l+16)
#pragma unroll
      for (int j = 0; j < 4; ++j) {
        float4 v = *(const float4*)(wr + j * 4);
        whh[g][j*4+0] = v.x; whh[g][j*4+1] = v.y; whh[g][j*4+2] = v.z; whh[g][j*4+3] = v.w;
      }
      float4 u = *(const float4*)(w_ih1 + row * FIN + lane * 4);
      wih[g][0] = u.x; wih[g][1] = u.y; wih[g][2] = u.z; wih[g][3] = u.w;
      bz[g] = b_ih1[row] + b_hh1[row];
    }
    float cst = 0.f;                                   // cell state (replicated per lane)

    for (int t = 0; t < TSTEPS; ++t) {
      if (t >= 1)
        wg_wait(ws, wave, lane,
                0u,   32u * (uint32_t)t,                                  // h1[t-1] produced
                512u, (t >= 2) ? 16u * (uint32_t)(t - 1) : 0u);           // L2 staged h1[t-2] (WAR guard)

      // stage h1[t-1] -> LDS (swizzled to break the stride-64B bank conflict)
      if (t >= 1) {
        float* src = h1buf + ((t - 1) & 1) * HD + tid * 4;
        float a0 = __hip_atomic_load(src + 0, __ATOMIC_RELAXED, AG);
        float a1 = __hip_atomic_load(src + 1, __ATOMIC_RELAXED, AG);
        float a2 = __hip_atomic_load(src + 2, __ATOMIC_RELAXED, AG);
        float a3 = __hip_atomic_load(src + 3, __ATOMIC_RELAXED, AG);
        hsl[tid ^ ((tid >> 3) & 7)] = make_float4(a0, a1, a2, a3);
      } else {
        hsl[tid] = make_float4(0.f, 0.f, 0.f, 0.f);
      }
      __syncthreads();

      float hv[16];
#pragma unroll
      for (int i = 0; i < 4; ++i) {
        int f = lane * 4 + i;
        float4 v = hsl[f ^ ((f >> 3) & 7)];
        hv[i*4+0] = v.x; hv[i*4+1] = v.y; hv[i*4+2] = v.z; hv[i*4+3] = v.w;
      }
      float4 xv = *(const float4*)(x + (size_t)t * FIN + lane * 4);

      float a0 = 0.f, a1 = 0.f, a2 = 0.f, a3 = 0.f;
#pragma unroll
      for (int j = 0; j < 16; ++j) {
        a0 = fmaf(whh[0][j], hv[j], a0);
        a1 = fmaf(whh[1][j], hv[j], a1);
        a2 = fmaf(whh[2][j], hv[j], a2);
        a3 = fmaf(whh[3][j], hv[j], a3);
      }
      a0 = fmaf(wih[0][0], xv.x, a0); a0 = fmaf(wih[0][1], xv.y, a0);
      a0 = fmaf(wih[0][2], xv.z, a0); a0 = fmaf(wih[0][3], xv.w, a0);
      a1 = fmaf(wih[1][0], xv.x, a1); a1 = fmaf(wih[1][1], xv.y, a1);
      a1 = fmaf(wih[1][2], xv.z, a1); a1 = fmaf(wih[1][3], xv.w, a1);
      a2 = fmaf(wih[2][0], xv.x, a2); a2 = fmaf(wih[2][1], xv.y, a2);
      a2 = fmaf(wih[2][2], xv.z, a2); a2 = fmaf(wih[2][3], xv.w, a2);
      a3 = fmaf(wih[3][0], xv.x, a3); a3 = fmaf(wih[3][1], xv.y, a3);
      a3 = fmaf(wih[3][2], xv.z, a3); a3 = fmaf(wih[3][3], xv.w, a3);

#pragma unroll
      for (int d = 1; d < 64; d <<= 1) {               // full-wave butterfly: all lanes get sums
        a0 += __shfl_xor(a0, d, 64);
        a1 += __shfl_xor(a1, d, 64);
        a2 += __shfl_xor(a2, d, 64);
        a3 += __shfl_xor(a3, d, 64);
      }
      float ig = sigf(a0 + bz[0]);
      float fg = sigf(a1 + bz[1]);
      float gg = tanhf(a2 + bz[2]);
      float og = sigf(a3 + bz[3]);
      cst = fg * cst + ig * gg;
      float h = og * tanhf(cst);

      if (lane == 0)
        __hip_atomic_store(&h1buf[(t & 1) * HD + hb], h, __ATOMIC_RELAXED, AG);
      asm volatile("s_waitcnt vmcnt(0)" ::: "memory");
      __syncthreads();
      if (tid == 0)
        __hip_atomic_fetch_add(&ws[(uint32_t)(bid & 7) * 64u], 1u, __ATOMIC_RELEASE, AG);
    }
  } else {
    // ------------------------- layer 2 -------------------------
    const int e = (bid - 256) * 4 + wave;              // h2 index 0..511
    float wih2[4][16], whh2[4][8], bz[4];
#pragma unroll
    for (int g = 0; g < 4; ++g) {
      const size_t row = (size_t)g * ED + e;
      const float* wr = w_ih2 + row * HD + lane * 16;
#pragma unroll
      for (int j = 0; j < 4; ++j) {
        float4 v = *(const float4*)(wr + j * 4);
        wih2[g][j*4+0] = v.x; wih2[g][j*4+1] = v.y; wih2[g][j*4+2] = v.z; wih2[g][j*4+3] = v.w;
      }
      const float* wr2 = w_hh2 + row * ED + lane * 8;
      float4 v0 = *(const float4*)(wr2);
      float4 v1 = *(const float4*)(wr2 + 4);
      whh2[g][0]=v0.x; whh2[g][1]=v0.y; whh2[g][2]=v0.z; whh2[g][3]=v0.w;
      whh2[g][4]=v1.x; whh2[g][5]=v1.y; whh2[g][6]=v1.z; whh2[g][7]=v1.w;
      bz[g] = b_ih2[row] + b_hh2[row];
    }
    float cst = 0.f;

    for (int s = 0; s < TSTEPS; ++s) {
      wg_wait(ws, wave, lane,
              0u,    32u * (uint32_t)(s + 1),                        // h1[s] produced
              1024u, (s >= 1) ? 16u * (uint32_t)s : 0u);             // h2[s-1] produced

      {
        float* src = h1buf + (s & 1) * HD + tid * 4;
        float a0 = __hip_atomic_load(src + 0, __ATOMIC_RELAXED, AG);
        float a1 = __hip_atomic_load(src + 1, __ATOMIC_RELAXED, AG);
        float a2 = __hip_atomic_load(src + 2, __ATOMIC_RELAXED, AG);
        float a3 = __hip_atomic_load(src + 3, __ATOMIC_RELAXED, AG);
        hsl[tid ^ ((tid >> 3) & 7)] = make_float4(a0, a1, a2, a3);
      }
      if (tid < 128) {
        if (s >= 1) {
          float* src = h2buf + ((s - 1) & 1) * ED + tid * 4;
          float a0 = __hip_atomic_load(src + 0, __ATOMIC_RELAXED, AG);
          float a1 = __hip_atomic_load(src + 1, __ATOMIC_RELAXED, AG);
          float a2 = __hip_atomic_load(src + 2, __ATOMIC_RELAXED, AG);
          float a3 = __hip_atomic_load(src + 3, __ATOMIC_RELAXED, AG);
          h2l[tid ^ ((tid >> 3) & 7)] = make_float4(a0, a1, a2, a3);
        } else {
          h2l[tid] = make_float4(0.f, 0.f, 0.f, 0.f);
        }
      }
      __syncthreads();
      if (tid == 0)  // publish "h1[s] staged" early so L1 can reuse the slot
        __hip_atomic_fetch_add(&ws[512u + (uint32_t)(bid & 7) * 64u], 1u, __ATOMIC_RELAXED, AG);

      float hv[16];
#pragma unroll
      for (int i = 0; i < 4; ++i) {
        int f = lane * 4 + i;
        float4 v = hsl[f ^ ((f >> 3) & 7)];
        hv[i*4+0] = v.x; hv[i*4+1] = v.y; hv[i*4+2] = v.z; hv[i*4+3] = v.w;
      }
      float gv[8];
#pragma unroll
      for (int i = 0; i < 2; ++i) {
        int f = lane * 2 + i;
        float4 v = h2l[f ^ ((f >> 3) & 7)];
        gv[i*4+0] = v.x; gv[i*4+1] = v.y; gv[i*4+2] = v.z; gv[i*4+3] = v.w;
      }

      float a0 = 0.f, a1 = 0.f, a2 = 0.f, a3 = 0.f;
#pragma unroll
      for (int j = 0; j < 16; ++j) {
        a0 = fmaf(wih2[0][j], hv[j], a0);
        a1 = fmaf(wih2[1][j], hv[j], a1);
        a2 = fmaf(wih2[2][j], hv[j], a2);
        a3 = fmaf(wih2[3][j], hv[j], a3);
      }
#pragma unroll
      for (int j = 0; j < 8; ++j) {
        a0 = fmaf(whh2[0][j], gv[j], a0);
        a1 = fmaf(whh2[1][j], gv[j], a1);
        a2 = fmaf(whh2[2][j], gv[j], a2);
        a3 = fmaf(whh2[3][j], gv[j], a3);
      }
#pragma unroll
      for (int d = 1; d < 64; d <<= 1) {
        a0 += __shfl_xor(a0, d, 64);
        a1 += __shfl_xor(a1, d, 64);
        a2 += __shfl_xor(a2, d, 64);
        a3 += __shfl_xor(a3, d, 64);
      }
      float ig = sigf(a0 + bz[0]);
      float fg = sigf(a1 + bz[1]);
      float gg = tanhf(a2 + bz[2]);
      float og = sigf(a3 + bz[3]);
      cst = fg * cst + ig * gg;
      float h = og * tanhf(cst);

      if (lane == 0) {
        __hip_atomic_store(&h2buf[(s & 1) * ED + e], h, __ATOMIC_RELAXED, AG);
        if (s == TSTEPS - 1) out[e] = h;               // final hidden -> d_out
      }
      asm volatile("s_waitcnt vmcnt(0)" ::: "memory");
      __syncthreads();
      if (tid == 0)
        __hip_atomic_fetch_add(&ws[1024u + (uint32_t)(bid & 7) * 64u], 1u, __ATOMIC_RELEASE, AG);
    }
  }
}

extern "C" void kernel_launch(void* const* d_in, const int* in_sizes, int n_in,
                              void* d_out, int out_size, void* d_ws, size_t ws_size,
                              hipStream_t stream) {
  const float* x    = (const float*)d_in[0];
  const float* wih1 = (const float*)d_in[1];
  const float* whh1 = (const float*)d_in[2];
  const float* bih1 = (const float*)d_in[3];
  const float* bhh1 = (const float*)d_in[4];
  const float* wih2 = (const float*)d_in[5];
  const float* whh2 = (const float*)d_in[6];
  const float* bih2 = (const float*)d_in[7];
  const float* bhh2 = (const float*)d_in[8];
  float* out   = (float*)d_out;
  uint32_t* ws = (uint32_t*)d_ws;

  hipLaunchKernelGGL(zero_ctrs, dim3(1), dim3(64), 0, stream, ws);
  // 384 wgs x 256 thr, <=2 wgs/CU by __launch_bounds__(256,2): all co-resident
  // on 256 CUs, so the persistent spin protocol cannot deadlock.
  hipLaunchKernelGGL(lstm2_fused, dim3(384), dim3(256), 0, stream,
                     x, wih1, whh1, bih1, bhh1, wih2, whh2, bih2, bhh2, out, ws);
}

// Round 2
// 63060.303 us; speedup vs baseline: 1.3895x; 1.3895x over previous
//
#include <hip/hip_runtime.h>
#include <cstdint>

#define TSTEPS 8192
#define FIN 256
#define HD 1024
#define ED 512
#define W1 128   // layer-1 workgroups (each: 4 waves x 2 h-outputs)
#define W2 64    // layer-2 workgroups
#define RING 4   // h ring depth

#define AG __HIP_MEMORY_SCOPE_AGENT
typedef unsigned long long u64;
typedef unsigned int u32;
typedef u32 u32x4 __attribute__((ext_vector_type(4)));
typedef u32 u32x2 __attribute__((ext_vector_type(2)));

// ---- ws layout ----
// u64 pair1[RING][HD]   @ 0         (32 KB)  (tag in low dword, value in high)
// u64 pair2[RING][ED]   @ +4096 u64 (16 KB)
// u32 cons1[W1]         @ +12288 u32        L1 wg progress (staged h1[t-1] => t)
// u32 cons2[W2]                              L2 wg progress (staged h1[s],h2[s-1] => s)

__global__ void zero_ctrs(u32* ws32) {
  int i = threadIdx.x;
  if (i < W1 + W2) ws32[(RING * HD + RING * ED) * 2 + i] = 0u;
}

__device__ __forceinline__ float sigf(float z) { return 1.0f / (1.0f + expf(-z)); }
__device__ __forceinline__ float uaf(u32 v) { return __uint_as_float(v); }

__device__ __forceinline__ void pair_store(u64* p, int t, float h) {
  u64 pk = ((u64)__float_as_uint(h) << 32) | (u64)(u32)t;
  __hip_atomic_store(p, pk, __ATOMIC_RELAXED, AG);  // single 8B atomic: tag+val can't tear
}

// Persistent fused 2-layer LSTM. 192 wgs x 256 thr, all co-resident (1 wg/CU fits
// trivially with __launch_bounds__(256,1); grid < 256 CUs).
//  wg 0..127   : layer 1, wave w owns h1 idx {bid*8+w*2, +1}; lane owns k-chunk 16l..16l+15
//  wg 128..191 : layer 2, wave w owns h2 idx {(bid-128)*8+w*2, +1}
// Weights live in VGPRs for the whole kernel. h exchange = (tag,val) pairs at the
// coherence point: producer does ONE fire-and-forget 8B store; consumer's poll load
// returns data+tag together (single MALL round trip, no RMW, no release fence).
__global__ void __launch_bounds__(256, 1) lstm2_fused(
    const float* __restrict__ x,
    const float* __restrict__ w_ih1, const float* __restrict__ w_hh1,
    const float* __restrict__ b_ih1, const float* __restrict__ b_hh1,
    const float* __restrict__ w_ih2, const float* __restrict__ w_hh2,
    const float* __restrict__ b_ih2, const float* __restrict__ b_hh2,
    float* __restrict__ out, u32* __restrict__ ws32)
{
  u64* pair1 = (u64*)ws32;
  u64* pair2 = pair1 + RING * HD;
  u32* cons1 = (u32*)(pair2 + RING * ED);
  u32* cons2 = cons1 + W1;

  const int bid  = blockIdx.x;
  const int tid  = threadIdx.x;
  const int wave = tid >> 6;
  const int lane = tid & 63;

  __shared__ float4 hsl[256];  // h1 staging (XOR-swizzled float4 slots)
  __shared__ float4 h2l[128];  // h2 staging

  if (bid < W1) {
    // ------------------------------ layer 1 ------------------------------
    const int h0 = bid * 8 + wave * 2;
    float whh[2][4][16], wih[2][4][4], bz[2][4];
#pragma unroll
    for (int r = 0; r < 2; ++r)
#pragma unroll
      for (int g = 0; g < 4; ++g) {
        const size_t row = (size_t)g * HD + (h0 + r);   // PyTorch gate order i,f,g,o
        const float* wr = w_hh1 + row * HD + lane * 16;
#pragma unroll
        for (int j = 0; j < 4; ++j) {
          float4 v = *(const float4*)(wr + j * 4);
          whh[r][g][j*4+0] = v.x; whh[r][g][j*4+1] = v.y;
          whh[r][g][j*4+2] = v.z; whh[r][g][j*4+3] = v.w;
        }
        float4 u = *(const float4*)(w_ih1 + row * FIN + lane * 4);
        wih[r][g][0] = u.x; wih[r][g][1] = u.y; wih[r][g][2] = u.z; wih[r][g][3] = u.w;
        bz[r][g] = b_ih1[row] + b_hh1[row];
      }
    float cst[2] = {0.f, 0.f};

    for (int t = 0; t < TSTEPS; ++t) {
      float4 xv = *(const float4*)(x + (size_t)t * FIN + lane * 4);  // cached, hides under poll

      if (t == 0) {
        hsl[tid] = make_float4(0.f, 0.f, 0.f, 0.f);
      } else if (wave == 0) {
        // ---- fused poll+stage: one round trip; includes ring back-pressure ----
        const u64* pb  = pair1 + ((t - 1) & 3) * HD + lane * 16;  // 16 pairs = 128B
        const u32* c1p = cons1 + lane * 2;
        const u32* c2p = cons2 + lane;
        const u32 want = (u32)(t - 1);
        const int bp1 = t - 3, bp2 = t - 4;
        u32x4 q0, q1, q2, q3, q4, q5, q6, q7; u32x2 c1v; u32 c2v;
        for (;;) {
          asm volatile(
            "global_load_dwordx4 %0, %10, off sc0 sc1\n\t"
            "global_load_dwordx4 %1, %10, off offset:16 sc0 sc1\n\t"
            "global_load_dwordx4 %2, %10, off offset:32 sc0 sc1\n\t"
            "global_load_dwordx4 %3, %10, off offset:48 sc0 sc1\n\t"
            "global_load_dwordx4 %4, %10, off offset:64 sc0 sc1\n\t"
            "global_load_dwordx4 %5, %10, off offset:80 sc0 sc1\n\t"
            "global_load_dwordx4 %6, %10, off offset:96 sc0 sc1\n\t"
            "global_load_dwordx4 %7, %10, off offset:112 sc0 sc1\n\t"
            "global_load_dwordx2 %8, %11, off sc0 sc1\n\t"
            "global_load_dword %9, %12, off sc0 sc1\n\t"
            "s_waitcnt vmcnt(0)"
            : "=&v"(q0), "=&v"(q1), "=&v"(q2), "=&v"(q3),
              "=&v"(q4), "=&v"(q5), "=&v"(q6), "=&v"(q7),
              "=&v"(c1v), "=&v"(c2v)
            : "v"(pb), "v"(c1p), "v"(c2p)
            : "memory");
          bool ok = (q0.x == want) & (q0.z == want) & (q1.x == want) & (q1.z == want)
                  & (q2.x == want) & (q2.z == want) & (q3.x == want) & (q3.z == want)
                  & (q4.x == want) & (q4.z == want) & (q5.x == want) & (q5.z == want)
                  & (q6.x == want) & (q6.z == want) & (q7.x == want) & (q7.z == want)
                  & ((int)c1v.x >= bp1) & ((int)c1v.y >= bp1) & ((int)c2v >= bp2);
          if (__all(ok)) break;
        }
        if (lane == 0)  // slot consumed into regs -> publish progress (plain store, no RMW)
          __hip_atomic_store(cons1 + bid, (u32)t, __ATOMIC_RELAXED, AG);
        const int f0 = lane * 4;
        hsl[(f0+0) ^ (((f0+0) >> 3) & 7)] = make_float4(uaf(q0.y), uaf(q0.w), uaf(q1.y), uaf(q1.w));
        hsl[(f0+1) ^ (((f0+1) >> 3) & 7)] = make_float4(uaf(q2.y), uaf(q2.w), uaf(q3.y), uaf(q3.w));
        hsl[(f0+2) ^ (((f0+2) >> 3) & 7)] = make_float4(uaf(q4.y), uaf(q4.w), uaf(q5.y), uaf(q5.w));
        hsl[(f0+3) ^ (((f0+3) >> 3) & 7)] = make_float4(uaf(q6.y), uaf(q6.w), uaf(q7.y), uaf(q7.w));
      }
      __syncthreads();

      float hv[16];
#pragma unroll
      for (int i = 0; i < 4; ++i) {
        int f = lane * 4 + i;
        float4 v = hsl[f ^ ((f >> 3) & 7)];
        hv[i*4+0] = v.x; hv[i*4+1] = v.y; hv[i*4+2] = v.z; hv[i*4+3] = v.w;
      }
      __syncthreads();   // all waves copied hv -> hsl free for next step's staging

      float acc[2][4] = {{0.f,0.f,0.f,0.f},{0.f,0.f,0.f,0.f}};
#pragma unroll
      for (int j = 0; j < 16; ++j) {
        float hj = hv[j];
#pragma unroll
        for (int r = 0; r < 2; ++r)
#pragma unroll
          for (int g = 0; g < 4; ++g)
            acc[r][g] = fmaf(whh[r][g][j], hj, acc[r][g]);
      }
#pragma unroll
      for (int r = 0; r < 2; ++r)
#pragma unroll
        for (int g = 0; g < 4; ++g) {
          acc[r][g] = fmaf(wih[r][g][0], xv.x, acc[r][g]);
          acc[r][g] = fmaf(wih[r][g][1], xv.y, acc[r][g]);
          acc[r][g] = fmaf(wih[r][g][2], xv.z, acc[r][g]);
          acc[r][g] = fmaf(wih[r][g][3], xv.w, acc[r][g]);
        }
#pragma unroll
      for (int d = 1; d < 64; d <<= 1)
#pragma unroll
        for (int r = 0; r < 2; ++r)
#pragma unroll
          for (int g = 0; g < 4; ++g)
            acc[r][g] += __shfl_xor(acc[r][g], d, 64);

      float hval[2];
#pragma unroll
      for (int r = 0; r < 2; ++r) {
        float ig = sigf(acc[r][0] + bz[r][0]);
        float fg = sigf(acc[r][1] + bz[r][1]);
        float gg = tanhf(acc[r][2] + bz[r][2]);
        float og = sigf(acc[r][3] + bz[r][3]);
        cst[r] = fg * cst[r] + ig * gg;
        hval[r] = og * tanhf(cst[r]);
      }
      if (lane == 0) {
        u64* dst = pair1 + (t & 3) * HD + h0;
        pair_store(dst + 0, t, hval[0]);
        pair_store(dst + 1, t, hval[1]);
      }
    }
  } else {
    // ------------------------------ layer 2 ------------------------------
    const int jwg = bid - W1;
    const int e0 = jwg * 8 + wave * 2;
    float wih2[2][4][16], whh2[2][4][8], bz[2][4];
#pragma unroll
    for (int r = 0; r < 2; ++r)
#pragma unroll
      for (int g = 0; g < 4; ++g) {
        const size_t row = (size_t)g * ED + (e0 + r);
        const float* wr = w_ih2 + row * HD + lane * 16;
#pragma unroll
        for (int j = 0; j < 4; ++j) {
          float4 v = *(const float4*)(wr + j * 4);
          wih2[r][g][j*4+0] = v.x; wih2[r][g][j*4+1] = v.y;
          wih2[r][g][j*4+2] = v.z; wih2[r][g][j*4+3] = v.w;
        }
        const float* wr2 = w_hh2 + row * ED + lane * 8;
        float4 v0 = *(const float4*)(wr2);
        float4 v1 = *(const float4*)(wr2 + 4);
        whh2[r][g][0]=v0.x; whh2[r][g][1]=v0.y; whh2[r][g][2]=v0.z; whh2[r][g][3]=v0.w;
        whh2[r][g][4]=v1.x; whh2[r][g][5]=v1.y; whh2[r][g][6]=v1.z; whh2[r][g][7]=v1.w;
        bz[r][g] = b_ih2[row] + b_hh2[row];
      }
    float cst[2] = {0.f, 0.f};

    for (int s = 0; s < TSTEPS; ++s) {
      if (wave == 0) {
        // poll h1[s] pairs + own-ring back-pressure
        const u64* pb  = pair1 + (s & 3) * HD + lane * 16;
        const u32* c2p = cons2 + lane;
        const u32 want = (u32)s;
        const int bp = s - 3;
        u32x4 q0, q1, q2, q3, q4, q5, q6, q7; u32 c2v;
        for (;;) {
          asm volatile(
            "global_load_dwordx4 %0, %9, off sc0 sc1\n\t"
            "global_load_dwordx4 %1, %9, off offset:16 sc0 sc1\n\t"
            "global_load_dwordx4 %2, %9, off offset:32 sc0 sc1\n\t"
            "global_load_dwordx4 %3, %9, off offset:48 sc0 sc1\n\t"
            "global_load_dwordx4 %4, %9, off offset:64 sc0 sc1\n\t"
            "global_load_dwordx4 %5, %9, off offset:80 sc0 sc1\n\t"
            "global_load_dwordx4 %6, %9, off offset:96 sc0 sc1\n\t"
            "global_load_dwordx4 %7, %9, off offset:112 sc0 sc1\n\t"
            "global_load_dword %8, %10, off sc0 sc1\n\t"
            "s_waitcnt vmcnt(0)"
            : "=&v"(q0), "=&v"(q1), "=&v"(q2), "=&v"(q3),
              "=&v"(q4), "=&v"(q5), "=&v"(q6), "=&v"(q7), "=&v"(c2v)
            : "v"(pb), "v"(c2p)
            : "memory");
          bool ok = (q0.x == want) & (q0.z == want) & (q1.x == want) & (q1.z == want)
                  & (q2.x == want) & (q2.z == want) & (q3.x == want) & (q3.z == want)
                  & (q4.x == want) & (q4.z == want) & (q5.x == want) & (q5.z == want)
                  & (q6.x == want) & (q6.z == want) & (q7.x == want) & (q7.z == want)
                  & ((int)c2v >= bp);
          if (__all(ok)) break;
        }
        const int f0 = lane * 4;
        hsl[(f0+0) ^ (((f0+0) >> 3) & 7)] = make_float4(uaf(q0.y), uaf(q0.w), uaf(q1.y), uaf(q1.w));
        hsl[(f0+1) ^ (((f0+1) >> 3) & 7)] = make_float4(uaf(q2.y), uaf(q2.w), uaf(q3.y), uaf(q3.w));
        hsl[(f0+2) ^ (((f0+2) >> 3) & 7)] = make_float4(uaf(q4.y), uaf(q4.w), uaf(q5.y), uaf(q5.w));
        hsl[(f0+3) ^ (((f0+3) >> 3) & 7)] = make_float4(uaf(q6.y), uaf(q6.w), uaf(q7.y), uaf(q7.w));
      } else if (wave == 1 && s >= 1) {
        const u64* pb2 = pair2 + ((s - 1) & 3) * ED + lane * 8;  // 8 pairs = 64B
        const u32 want = (u32)(s - 1);
        u32x4 q0, q1, q2, q3;
        for (;;) {
          asm volatile(
            "global_load_dwordx4 %0, %4, off sc0 sc1\n\t"
            "global_load_dwordx4 %1, %4, off offset:16 sc0 sc1\n\t"
            "global_load_dwordx4 %2, %4, off offset:32 sc0 sc1\n\t"
            "global_load_dwordx4 %3, %4, off offset:48 sc0 sc1\n\t"
            "s_waitcnt vmcnt(0)"
            : "=&v"(q0), "=&v"(q1), "=&v"(q2), "=&v"(q3)
            : "v"(pb2)
            : "memory");
          bool ok = (q0.x == want) & (q0.z == want) & (q1.x == want) & (q1.z == want)
                  & (q2.x == want) & (q2.z == want) & (q3.x == want) & (q3.z == want);
          if (__all(ok)) break;
        }
        const int f0 = lane * 2;
        h2l[(f0+0) ^ (((f0+0) >> 3) & 7)] = make_float4(uaf(q0.y), uaf(q0.w), uaf(q1.y), uaf(q1.w));
        h2l[(f0+1) ^ (((f0+1) >> 3) & 7)] = make_float4(uaf(q2.y), uaf(q2.w), uaf(q3.y), uaf(q3.w));
      }
      if (s == 0 && tid < 128) h2l[tid] = make_float4(0.f, 0.f, 0.f, 0.f);
      __syncthreads();
      if (tid == 0)  // staged h1[s] and h2[s-1] -> publish progress
        __hip_atomic_store(cons2 + jwg, (u32)s, __ATOMIC_RELAXED, AG);

      float hv[16];
#pragma unroll
      for (int i = 0; i < 4; ++i) {
        int f = lane * 4 + i;
        float4 v = hsl[f ^ ((f >> 3) & 7)];
        hv[i*4+0] = v.x; hv[i*4+1] = v.y; hv[i*4+2] = v.z; hv[i*4+3] = v.w;
      }
      float gv[8];
#pragma unroll
      for (int i = 0; i < 2; ++i) {
        int f = lane * 2 + i;
        float4 v = h2l[f ^ ((f >> 3) & 7)];
        gv[i*4+0] = v.x; gv[i*4+1] = v.y; gv[i*4+2] = v.z; gv[i*4+3] = v.w;
      }
      __syncthreads();

      float acc[2][4] = {{0.f,0.f,0.f,0.f},{0.f,0.f,0.f,0.f}};
#pragma unroll
      for (int j = 0; j < 16; ++j) {
        float hj = hv[j];
#pragma unroll
        for (int r = 0; r < 2; ++r)
#pragma unroll
          for (int g = 0; g < 4; ++g)
            acc[r][g] = fmaf(wih2[r][g][j], hj, acc[r][g]);
      }
#pragma unroll
      for (int j = 0; j < 8; ++j) {
        float gj = gv[j];
#pragma unroll
        for (int r = 0; r < 2; ++r)
#pragma unroll
          for (int g = 0; g < 4; ++g)
            acc[r][g] = fmaf(whh2[r][g][j], gj, acc[r][g]);
      }
#pragma unroll
      for (int d = 1; d < 64; d <<= 1)
#pragma unroll
        for (int r = 0; r < 2; ++r)
#pragma unroll
          for (int g = 0; g < 4; ++g)
            acc[r][g] += __shfl_xor(acc[r][g], d, 64);

      float hval[2];
#pragma unroll
      for (int r = 0; r < 2; ++r) {
        float ig = sigf(acc[r][0] + bz[r][0]);
        float fg = sigf(acc[r][1] + bz[r][1]);
        float gg = tanhf(acc[r][2] + bz[r][2]);
        float og = sigf(acc[r][3] + bz[r][3]);
        cst[r] = fg * cst[r] + ig * gg;
        hval[r] = og * tanhf(cst[r]);
      }
      if (lane == 0) {
        u64* dst = pair2 + (s & 3) * ED + e0;
        pair_store(dst + 0, s, hval[0]);
        pair_store(dst + 1, s, hval[1]);
        if (s == TSTEPS - 1) { out[e0] = hval[0]; out[e0 + 1] = hval[1]; }
      }
    }
  }
}

extern "C" void kernel_launch(void* const* d_in, const int* in_sizes, int n_in,
                              void* d_out, int out_size, void* d_ws, size_t ws_size,
                              hipStream_t stream) {
  const float* x    = (const float*)d_in[0];
  const float* wih1 = (const float*)d_in[1];
  const float* whh1 = (const float*)d_in[2];
  const float* bih1 = (const float*)d_in[3];
  const float* bhh1 = (const float*)d_in[4];
  const float* wih2 = (const float*)d_in[5];
  const float* whh2 = (const float*)d_in[6];
  const float* bih2 = (const float*)d_in[7];
  const float* bhh2 = (const float*)d_in[8];
  float* out = (float*)d_out;
  u32* ws    = (u32*)d_ws;

  hipLaunchKernelGGL(zero_ctrs, dim3(1), dim3(256), 0, stream, ws);
  hipLaunchKernelGGL(lstm2_fused, dim3(W1 + W2), dim3(256), 0, stream,
                     x, wih1, whh1, bih1, bhh1, wih2, whh2, bih2, bhh2, out, ws);
}

// Round 3
// 36210.974 us; speedup vs baseline: 2.4198x; 1.7415x over previous
//
#include <hip/hip_runtime.h>
#include <cstdint>

#define TSTEPS 8192
#define FIN 256
#define HD 1024
#define ED 512
#define W1 128   // layer-1 wgs: wave owns 2 rows, lane parity picks row
#define W2 64    // layer-2 wgs

#define AG __HIP_MEMORY_SCOPE_AGENT
typedef unsigned long long u64;
typedef unsigned int u32;
typedef u32 u32x4 __attribute__((ext_vector_type(4)));
typedef u32 u32x2 __attribute__((ext_vector_type(2)));

// ---- ws layout ----
// u64 pair1[4][HD] @ u64 0      (32 KB)   (tag lo-dword, value hi-dword)
// u64 pair2[4][ED] @ u64 4096   (16 KB)
// u32 done1[W1]    @ u32 12288            L1 wg completed step tag (init -1)
// u32 done2[W2]    @ u32 12416            L2 wg completed step tag
// u32 cons2[W2]    @ u32 12480            L2 wg staged-h1 tag (ring WAR guard)
#define DONE1_OFS 12288
#define DONE2_OFS 12416
#define CONS2_OFS 12480

__global__ void init_ctrs(u32* ws32) {
  int i = threadIdx.x;
  if (i < 256) ws32[DONE1_OFS + i] = 0xFFFFFFFFu;   // done1,done2,cons2 = -1
}

__device__ __forceinline__ float sigf(float z) { return 1.0f / (1.0f + expf(-z)); }
__device__ __forceinline__ float uaf(u32 v) { return __uint_as_float(v); }

// 8x dwordx4 bulk load of 16 (tag,val) pairs/lane + tag verify (one round trip).
#define BULK16(pb, want, OK, q0,q1,q2,q3,q4,q5,q6,q7)                          \
  asm volatile(                                                                \
    "global_load_dwordx4 %0, %8, off sc0 sc1\n\t"                              \
    "global_load_dwordx4 %1, %8, off offset:16 sc0 sc1\n\t"                    \
    "global_load_dwordx4 %2, %8, off offset:32 sc0 sc1\n\t"                    \
    "global_load_dwordx4 %3, %8, off offset:48 sc0 sc1\n\t"                    \
    "global_load_dwordx4 %4, %8, off offset:64 sc0 sc1\n\t"                    \
    "global_load_dwordx4 %5, %8, off offset:80 sc0 sc1\n\t"                    \
    "global_load_dwordx4 %6, %8, off offset:96 sc0 sc1\n\t"                    \
    "global_load_dwordx4 %7, %8, off offset:112 sc0 sc1\n\t"                   \
    "s_waitcnt vmcnt(0)"                                                       \
    : "=&v"(q0), "=&v"(q1), "=&v"(q2), "=&v"(q3),                              \
      "=&v"(q4), "=&v"(q5), "=&v"(q6), "=&v"(q7)                               \
    : "v"(pb) : "memory");                                                     \
  OK = (q0.x==want)&(q0.z==want)&(q1.x==want)&(q1.z==want)                     \
     & (q2.x==want)&(q2.z==want)&(q3.x==want)&(q3.z==want)                     \
     & (q4.x==want)&(q4.z==want)&(q5.x==want)&(q5.z==want)                     \
     & (q6.x==want)&(q6.z==want)&(q7.x==want)&(q7.z==want);

// Persistent fused 2-layer LSTM, 192 wgs x 256 thr (1 wg/CU, all co-resident).
// Sync protocol: producers store (tag,val) pairs + a per-wg done tag (no fence);
// consumers spin on the 512B done/cons summaries only, then bulk-load pairs once
// and verify embedded tags (retry absorbs any store reordering).
__global__ void __launch_bounds__(256, 1) lstm2_fused(
    const float* __restrict__ x,
    const float* __restrict__ w_ih1, const float* __restrict__ w_hh1,
    const float* __restrict__ b_ih1, const float* __restrict__ b_hh1,
    const float* __restrict__ w_ih2, const float* __restrict__ w_hh2,
    const float* __restrict__ b_ih2, const float* __restrict__ b_hh2,
    float* __restrict__ out, u32* __restrict__ ws32)
{
  u64* pair1 = (u64*)ws32;
  u64* pair2 = pair1 + 4 * HD;
  u32* done1 = ws32 + DONE1_OFS;
  u32* done2 = ws32 + DONE2_OFS;
  u32* cons2 = ws32 + CONS2_OFS;

  const int bid  = blockIdx.x;
  const int tid  = threadIdx.x;
  const int wave = tid >> 6;
  const int lane = tid & 63;
  const int half = lane & 1;   // which of the wave's 2 rows this lane computes
  const int kc   = lane >> 1;  // k-chunk id 0..31

  __shared__ float4 hsl[256];  // h1 stage: slot s holds h1[4s..4s+3] (XOR-swizzled)
  __shared__ float4 h2l[128];  // h2 stage

  if (bid < W1) {
    // ------------------------------ layer 1 ------------------------------
    const int ro = bid * 8 + wave * 2 + half;       // owned gate-row (h1 index)
    const int kbase  = kc * 32;                     // 32 k-elems of w_hh per lane
    const int xkbase = kc * 8;                      // 8 k-elems of w_ih per lane
    float whh[4][32], wih[4][8], bz[4];
#pragma unroll
    for (int g = 0; g < 4; ++g) {                   // PyTorch gate order i,f,g,o
      const float* wr = w_hh1 + ((size_t)(g * HD + ro)) * HD + kbase;
#pragma unroll
      for (int j = 0; j < 8; ++j) {
        float4 v = *(const float4*)(wr + j * 4);
        whh[g][j*4+0] = v.x; whh[g][j*4+1] = v.y; whh[g][j*4+2] = v.z; whh[g][j*4+3] = v.w;
      }
      const float* ur = w_ih1 + ((size_t)(g * HD + ro)) * FIN + xkbase;
      float4 a = *(const float4*)(ur), b = *(const float4*)(ur + 4);
      wih[g][0]=a.x; wih[g][1]=a.y; wih[g][2]=a.z; wih[g][3]=a.w;
      wih[g][4]=b.x; wih[g][5]=b.y; wih[g][6]=b.z; wih[g][7]=b.w;
      bz[g] = b_ih1[g * HD + ro] + b_hh1[g * HD + ro];
    }
    float cst = 0.f;

    for (int t = 0; t < TSTEPS; ++t) {
      const float* xp = x + (size_t)t * FIN + xkbase;
      float4 xa = *(const float4*)(xp);
      float4 xb = *(const float4*)(xp + 4);

      if (t == 0) {
        hsl[tid] = make_float4(0.f, 0.f, 0.f, 0.f);
      } else if (wave == 0) {
        // ---- cheap detect: done1 (8B/lane) + cons2 ring guard (4B/lane) ----
        const u32* d1p = done1 + lane * 2;
        const u32* c2p = cons2 + lane;
        const int wd = t - 1, wc = t - 4;
        u32x2 dv; u32 cv;
        for (;;) {
          asm volatile(
            "global_load_dwordx2 %0, %2, off sc0 sc1\n\t"
            "global_load_dword %1, %3, off sc0 sc1\n\t"
            "s_waitcnt vmcnt(0)"
            : "=&v"(dv), "=&v"(cv) : "v"(d1p), "v"(c2p) : "memory");
          bool ok = ((int)dv.x >= wd) & ((int)dv.y >= wd) & ((int)cv >= wc);
          if (__all(ok)) break;
        }
        // ---- bulk fetch h1[t-1] once, verify embedded tags ----
        const u64* pb = pair1 + (size_t)((t - 1) & 3) * HD + lane * 16;
        const u32 want = (u32)(t - 1);
        u32x4 q0,q1,q2,q3,q4,q5,q6,q7; bool ok;
        for (;;) { BULK16(pb, want, ok, q0,q1,q2,q3,q4,q5,q6,q7); if (__all(ok)) break; }
        const int f0 = lane * 4;
        hsl[(f0+0) ^ (((f0+0)>>3)&7)] = make_float4(uaf(q0.y),uaf(q0.w),uaf(q1.y),uaf(q1.w));
        hsl[(f0+1) ^ (((f0+1)>>3)&7)] = make_float4(uaf(q2.y),uaf(q2.w),uaf(q3.y),uaf(q3.w));
        hsl[(f0+2) ^ (((f0+2)>>3)&7)] = make_float4(uaf(q4.y),uaf(q4.w),uaf(q5.y),uaf(q5.w));
        hsl[(f0+3) ^ (((f0+3)>>3)&7)] = make_float4(uaf(q6.y),uaf(q6.w),uaf(q7.y),uaf(q7.w));
      }
      __syncthreads();

      float hv[32];
#pragma unroll
      for (int j = 0; j < 8; ++j) {
        int f = kc * 8 + j;
        float4 v = hsl[f ^ ((f>>3)&7)];
        hv[j*4+0]=v.x; hv[j*4+1]=v.y; hv[j*4+2]=v.z; hv[j*4+3]=v.w;
      }

      float a0=0.f, a1=0.f, a2=0.f, a3=0.f;
#pragma unroll
      for (int j = 0; j < 32; ++j) {
        float hj = hv[j];
        a0 = fmaf(whh[0][j], hj, a0); a1 = fmaf(whh[1][j], hj, a1);
        a2 = fmaf(whh[2][j], hj, a2); a3 = fmaf(whh[3][j], hj, a3);
      }
      float xvv[8] = {xa.x,xa.y,xa.z,xa.w,xb.x,xb.y,xb.z,xb.w};
#pragma unroll
      for (int j = 0; j < 8; ++j) {
        float xj = xvv[j];
        a0 = fmaf(wih[0][j], xj, a0); a1 = fmaf(wih[1][j], xj, a1);
        a2 = fmaf(wih[2][j], xj, a2); a3 = fmaf(wih[3][j], xj, a3);
      }
#pragma unroll
      for (int d = 2; d < 64; d <<= 1) {   // parity-preserving butterfly (20 ops)
        a0 += __shfl_xor(a0, d, 64);
        a1 += __shfl_xor(a1, d, 64);
        a2 += __shfl_xor(a2, d, 64);
        a3 += __shfl_xor(a3, d, 64);
      }
      float ig = sigf(a0 + bz[0]);
      float fg = sigf(a1 + bz[1]);
      float gg = tanhf(a2 + bz[2]);
      float og = sigf(a3 + bz[3]);
      cst = fg * cst + ig * gg;
      float h = og * tanhf(cst);

      if (lane < 2) {   // lane0 stores row +0, lane1 row +1 (its own h)
        u64 pk = ((u64)__float_as_uint(h) << 32) | (u64)(u32)t;
        __hip_atomic_store(pair1 + (size_t)(t & 3) * HD + ro, pk, __ATOMIC_RELAXED, AG);
      }
      __builtin_amdgcn_s_barrier();   // raw: don't drain the in-flight pair stores
      if (tid == 0)
        __hip_atomic_store(done1 + bid, (u32)t, __ATOMIC_RELAXED, AG);
    }
  } else {
    // ------------------------------ layer 2 ------------------------------
    const int jwg = bid - W1;
    const int eo = jwg * 8 + wave * 2 + half;       // owned h2 index
    const int kbase  = kc * 32;                     // over HD (w_ih2)
    const int k2base = kc * 16;                     // over ED (w_hh2)
    float wA[4][32], wB[4][16], bz[4];
#pragma unroll
    for (int g = 0; g < 4; ++g) {
      const float* wr = w_ih2 + ((size_t)(g * ED + eo)) * HD + kbase;
#pragma unroll
      for (int j = 0; j < 8; ++j) {
        float4 v = *(const float4*)(wr + j * 4);
        wA[g][j*4+0]=v.x; wA[g][j*4+1]=v.y; wA[g][j*4+2]=v.z; wA[g][j*4+3]=v.w;
      }
      const float* wr2 = w_hh2 + ((size_t)(g * ED + eo)) * ED + k2base;
#pragma unroll
      for (int j = 0; j < 4; ++j) {
        float4 v = *(const float4*)(wr2 + j * 4);
        wB[g][j*4+0]=v.x; wB[g][j*4+1]=v.y; wB[g][j*4+2]=v.z; wB[g][j*4+3]=v.w;
      }
      bz[g] = b_ih2[g * ED + eo] + b_hh2[g * ED + eo];
    }
    float cst = 0.f;

    for (int s = 0; s < TSTEPS; ++s) {
      if (wave == 0) {
        // detect h1[s]: done1 >= s
        const u32* d1p = done1 + lane * 2;
        u32x2 dv;
        for (;;) {
          asm volatile(
            "global_load_dwordx2 %0, %1, off sc0 sc1\n\t"
            "s_waitcnt vmcnt(0)"
            : "=&v"(dv) : "v"(d1p) : "memory");
          bool ok = ((int)dv.x >= s) & ((int)dv.y >= s);
          if (__all(ok)) break;
        }
        const u64* pb = pair1 + (size_t)(s & 3) * HD + lane * 16;
        const u32 want = (u32)s;
        u32x4 q0,q1,q2,q3,q4,q5,q6,q7; bool ok;
        for (;;) { BULK16(pb, want, ok, q0,q1,q2,q3,q4,q5,q6,q7); if (__all(ok)) break; }
        if (lane == 0)   // h1[s] safely in registers -> release the ring slot
          __hip_atomic_store(cons2 + jwg, (u32)s, __ATOMIC_RELAXED, AG);
        const int f0 = lane * 4;
        hsl[(f0+0) ^ (((f0+0)>>3)&7)] = make_float4(uaf(q0.y),uaf(q0.w),uaf(q1.y),uaf(q1.w));
        hsl[(f0+1) ^ (((f0+1)>>3)&7)] = make_float4(uaf(q2.y),uaf(q2.w),uaf(q3.y),uaf(q3.w));
        hsl[(f0+2) ^ (((f0+2)>>3)&7)] = make_float4(uaf(q4.y),uaf(q4.w),uaf(q5.y),uaf(q5.w));
        hsl[(f0+3) ^ (((f0+3)>>3)&7)] = make_float4(uaf(q6.y),uaf(q6.w),uaf(q7.y),uaf(q7.w));
      } else if (wave == 1 && s >= 1) {
        // detect h2[s-1]: done2 >= s-1, then bulk 8 pairs/lane
        const u32* d2p = done2 + lane;
        const int wd = s - 1;
        u32 dv;
        for (;;) {
          asm volatile(
            "global_load_dword %0, %1, off sc0 sc1\n\t"
            "s_waitcnt vmcnt(0)"
            : "=&v"(dv) : "v"(d2p) : "memory");
          if (__all((int)dv >= wd)) break;
        }
        const u64* pb2 = pair2 + (size_t)((s - 1) & 3) * ED + lane * 8;
        const u32 want = (u32)(s - 1);
        u32x4 q0,q1,q2,q3; bool ok;
        for (;;) {
          asm volatile(
            "global_load_dwordx4 %0, %4, off sc0 sc1\n\t"
            "global_load_dwordx4 %1, %4, off offset:16 sc0 sc1\n\t"
            "global_load_dwordx4 %2, %4, off offset:32 sc0 sc1\n\t"
            "global_load_dwordx4 %3, %4, off offset:48 sc0 sc1\n\t"
            "s_waitcnt vmcnt(0)"
            : "=&v"(q0), "=&v"(q1), "=&v"(q2), "=&v"(q3)
            : "v"(pb2) : "memory");
          ok = (q0.x==want)&(q0.z==want)&(q1.x==want)&(q1.z==want)
             & (q2.x==want)&(q2.z==want)&(q3.x==want)&(q3.z==want);
          if (__all(ok)) break;
        }
        const int f0 = lane * 2;
        h2l[(f0+0) ^ (((f0+0)>>3)&7)] = make_float4(uaf(q0.y),uaf(q0.w),uaf(q1.y),uaf(q1.w));
        h2l[(f0+1) ^ (((f0+1)>>3)&7)] = make_float4(uaf(q2.y),uaf(q2.w),uaf(q3.y),uaf(q3.w));
      }
      if (s == 0 && tid < 128) h2l[tid] = make_float4(0.f, 0.f, 0.f, 0.f);
      __syncthreads();

      float hv[32];
#pragma unroll
      for (int j = 0; j < 8; ++j) {
        int f = kc * 8 + j;
        float4 v = hsl[f ^ ((f>>3)&7)];
        hv[j*4+0]=v.x; hv[j*4+1]=v.y; hv[j*4+2]=v.z; hv[j*4+3]=v.w;
      }
      float gv[16];
#pragma unroll
      for (int j = 0; j < 4; ++j) {
        int f = kc * 4 + j;
        float4 v = h2l[f ^ ((f>>3)&7)];
        gv[j*4+0]=v.x; gv[j*4+1]=v.y; gv[j*4+2]=v.z; gv[j*4+3]=v.w;
      }

      float a0=0.f, a1=0.f, a2=0.f, a3=0.f;
#pragma unroll
      for (int j = 0; j < 32; ++j) {
        float hj = hv[j];
        a0 = fmaf(wA[0][j], hj, a0); a1 = fmaf(wA[1][j], hj, a1);
        a2 = fmaf(wA[2][j], hj, a2); a3 = fmaf(wA[3][j], hj, a3);
      }
#pragma unroll
      for (int j = 0; j < 16; ++j) {
        float gj = gv[j];
        a0 = fmaf(wB[0][j], gj, a0); a1 = fmaf(wB[1][j], gj, a1);
        a2 = fmaf(wB[2][j], gj, a2); a3 = fmaf(wB[3][j], gj, a3);
      }
#pragma unroll
      for (int d = 2; d < 64; d <<= 1) {
        a0 += __shfl_xor(a0, d, 64);
        a1 += __shfl_xor(a1, d, 64);
        a2 += __shfl_xor(a2, d, 64);
        a3 += __shfl_xor(a3, d, 64);
      }
      float ig = sigf(a0 + bz[0]);
      float fg = sigf(a1 + bz[1]);
      float gg = tanhf(a2 + bz[2]);
      float og = sigf(a3 + bz[3]);
      cst = fg * cst + ig * gg;
      float h = og * tanhf(cst);

      if (lane < 2) {
        u64 pk = ((u64)__float_as_uint(h) << 32) | (u64)(u32)s;
        __hip_atomic_store(pair2 + (size_t)(s & 3) * ED + eo, pk, __ATOMIC_RELAXED, AG);
        if (s == TSTEPS - 1) out[eo] = h;
      }
      __builtin_amdgcn_s_barrier();
      if (tid == 0)
        __hip_atomic_store(done2 + jwg, (u32)s, __ATOMIC_RELAXED, AG);
    }
  }
}

extern "C" void kernel_launch(void* const* d_in, const int* in_sizes, int n_in,
                              void* d_out, int out_size, void* d_ws, size_t ws_size,
                              hipStream_t stream) {
  const float* x    = (const float*)d_in[0];
  const float* wih1 = (const float*)d_in[1];
  const float* whh1 = (const float*)d_in[2];
  const float* bih1 = (const float*)d_in[3];
  const float* bhh1 = (const float*)d_in[4];
  const float* wih2 = (const float*)d_in[5];
  const float* whh2 = (const float*)d_in[6];
  const float* bih2 = (const float*)d_in[7];
  const float* bhh2 = (const float*)d_in[8];
  float* out = (float*)d_out;
  u32* ws    = (u32*)d_ws;

  hipLaunchKernelGGL(init_ctrs, dim3(1), dim3(256), 0, stream, ws);
  hipLaunchKernelGGL(lstm2_fused, dim3(W1 + W2), dim3(256), 0, stream,
                     x, wih1, whh1, bih1, bhh1, wih2, whh2, bih2, bhh2, out, ws);
}